// Round 1
// baseline (1164.126 us; speedup 1.0000x reference)
//
#include <hip/hip_runtime.h>
#include <hip/hip_bf16.h>

#define HH 448
#define WW 608
#define CC 128
#define HWP (HH*WW)
#define SLOPE 0.01f

// ---------------- Kernel 1: classifier logits + softmax + loss + labels ----------------
// grid (448, 10), block 256. Each block: row h, 64-pixel tile.
__global__ __launch_bounds__(256) void k1_classify(
    const float* __restrict__ x, const float* __restrict__ x_gt,
    const float* __restrict__ Wc, const float* __restrict__ bc,
    float* __restrict__ loss_out, int* __restrict__ labels,
    float* __restrict__ xT, int use_xT)
{
    __shared__ float xs[128 * 65];   // [i][w], stride 65 (bank-conflict-free both ways)
    __shared__ float zt[128 * 64];   // [c][w]
    __shared__ float red[4 * 64];
    __shared__ float mrow[64];
    __shared__ float srow[64];

    const int h  = blockIdx.x;
    const int w0 = blockIdx.y * 64;
    const int t  = threadIdx.x;

    // ---- load x tile: x[i, h, w0+w] ----
    const float* xrow = x + (size_t)h * WW + w0;
    for (int e = t; e < 128 * 64; e += 256) {
        int i = e >> 6, w = e & 63;
        float v = (w0 + w < WW) ? xrow[(size_t)i * HWP + w] : 0.f;
        xs[i * 65 + w] = v;
    }
    __syncthreads();

    // ---- optional: write transposed per-pixel x vectors for kernel 2 ----
    if (use_xT) {
        for (int e = t; e < 128 * 64; e += 256) {
            int w = e >> 7, i = e & 127;          // lanes -> consecutive i: coalesced write
            if (w0 + w < WW) xT[((size_t)(h * WW + w0 + w)) * 128 + i] = xs[i * 65 + w];
        }
    }

    // ---- logits: wave wv owns classes [wv*32, wv*32+32), lane = pixel w ----
    const int wv = t >> 6, lane = t & 63;
    const int c0 = wv * 32;
    float acc[32];
    #pragma unroll
    for (int c = 0; c < 32; ++c) acc[c] = 0.f;

    const float* Wch = Wc + ((size_t)h * CC + c0) * 128;
    for (int i = 0; i < 128; i += 4) {
        float xv0 = xs[(i + 0) * 65 + lane];
        float xv1 = xs[(i + 1) * 65 + lane];
        float xv2 = xs[(i + 2) * 65 + lane];
        float xv3 = xs[(i + 3) * 65 + lane];
        #pragma unroll
        for (int c = 0; c < 32; ++c) {
            const float4 wv4 = *reinterpret_cast<const float4*>(Wch + c * 128 + i);
            acc[c] += wv4.x * xv0 + wv4.y * xv1 + wv4.z * xv2 + wv4.w * xv3;
        }
    }
    #pragma unroll
    for (int c = 0; c < 32; ++c) {
        float z = acc[c] + bc[h * CC + c0 + c];
        z = z > 0.f ? z : SLOPE * z;
        zt[(c0 + c) * 64 + lane] = z;
    }
    __syncthreads();

    // ---- softmax over classes per pixel; wave wv reduces its 32 classes ----
    float m = -1e30f;
    for (int c = c0; c < c0 + 32; ++c) m = fmaxf(m, zt[c * 64 + lane]);
    red[wv * 64 + lane] = m;
    __syncthreads();
    if (t < 64)
        mrow[lane] = fmaxf(fmaxf(red[lane], red[64 + lane]),
                           fmaxf(red[128 + lane], red[192 + lane]));
    __syncthreads();

    const float mm = mrow[lane];
    float s1 = 0.f;
    for (int c = c0; c < c0 + 32; ++c) {
        float tv = __expf(zt[c * 64 + lane] - mm);
        zt[c * 64 + lane] = tv;                 // keep e^{z-m} for later
        s1 += tv;
    }
    red[wv * 64 + lane] = s1;
    __syncthreads();
    if (t < 64)
        srow[lane] = red[lane] + red[64 + lane] + red[128 + lane] + red[192 + lane];
    __syncthreads();

    const float S1  = srow[lane];
    const float inv = 1.f / S1;
    float s2 = 0.f;
    for (int c = c0; c < c0 + 32; ++c) s2 += __expf(zt[c * 64 + lane] * inv);
    red[wv * 64 + lane] = s2;
    __syncthreads();

    if (t < 64 && (w0 + lane) < WW) {
        float S2 = red[lane] + red[64 + lane] + red[128 + lane] + red[192 + lane];
        int pix = h * WW + w0 + lane;
        float g = x_gt[pix];
        int lab = (int)(g * 128.f);
        lab = min(max(lab, 0), 127);
        float p_lab = zt[lab * 64 + lane] * inv;     // p[label] = e^{z-m}/S1
        loss_out[pix] = logf(S2) - p_lab;            // -(p_lab - logsumexp(p))
        labels[pix]   = lab;
    }
}

// ---------------- Kernel 2: per-(h, class) expert MLP ----------------
// grid (128, 448), block 256.
__global__ __launch_bounds__(256) void k2_experts(
    const float* __restrict__ x, const float* __restrict__ xT, int use_xT,
    const int* __restrict__ labels,
    const float* __restrict__ W1, const float* __restrict__ b1,
    const float* __restrict__ W2, const float* __restrict__ b2,
    const float* __restrict__ Wrc, const float* __restrict__ brc,
    float* __restrict__ out)
{
    const int c = blockIdx.x, h = blockIdx.y;
    __shared__ int   wlist[WW];
    __shared__ int   cnt;
    __shared__ float W1s[128 * 32];
    __shared__ float W2s[32 * 32];
    __shared__ float Wrcs[32 * 2];
    __shared__ float b1s[32], b2s[32], brcs[2];
    __shared__ float xsh[8][128];
    __shared__ float hs[8][33];
    __shared__ float h2s[8][33];

    const int t = threadIdx.x;
    if (t == 0) cnt = 0;
    __syncthreads();

    const int* lrow = labels + h * WW;
    for (int w = t; w < WW; w += 256) {
        if (lrow[w] == c) { int p = atomicAdd(&cnt, 1); wlist[p] = w; }
    }
    __syncthreads();
    const int k = cnt;
    if (k == 0) return;

    const size_t e = (size_t)h * 128 + c;
    const float* W1p = W1 + e * 4096;
    for (int i = t; i < 4096; i += 256) W1s[i] = W1p[i];
    const float* W2p = W2 + e * 1024;
    for (int i = t; i < 1024; i += 256) W2s[i] = W2p[i];
    if (t < 64) Wrcs[t] = Wrc[e * 64 + t];
    if (t < 32) { b1s[t] = b1[e * 32 + t]; b2s[t] = b2[e * 32 + t]; }
    if (t < 2)  brcs[t] = brc[e * 2 + t];
    __syncthreads();

    for (int base = 0; base < k; base += 8) {
        const int nb = min(8, k - base);
        for (int el = t; el < nb * 128; el += 256) {
            int j = el >> 7, i = el & 127;
            int w = wlist[base + j];
            xsh[j][i] = use_xT ? xT[((size_t)(h * WW + w)) * 128 + i]
                               : x[(size_t)i * HWP + h * WW + w];
        }
        __syncthreads();

        const int j = t >> 5, o = t & 31;
        if (j < nb) {
            float a = b1s[o];
            #pragma unroll 8
            for (int i = 0; i < 128; ++i) a += xsh[j][i] * W1s[i * 32 + o];
            hs[j][o] = a > 0.f ? a : SLOPE * a;
        }
        __syncthreads();
        if (j < nb) {
            float a = b2s[o];
            #pragma unroll
            for (int i = 0; i < 32; ++i) a += hs[j][i] * W2s[i * 32 + o];
            h2s[j][o] = a > 0.f ? a : SLOPE * a;
        }
        __syncthreads();
        if (j < nb && o < 2) {
            float a = brcs[o];
            #pragma unroll
            for (int i = 0; i < 32; ++i) a += h2s[j][i] * Wrcs[i * 2 + o];
            a = a > 0.f ? a : SLOPE * a;
            int w = wlist[base + j];
            int pix = h * WW + w;
            if (o == 1) out[HWP + pix] = a;                          // mask
            else        out[pix] = ((float)c + a) * (1.0f / 128.0f); // x_pos
        }
        __syncthreads();
    }
}

extern "C" void kernel_launch(void* const* d_in, const int* in_sizes, int n_in,
                              void* d_out, int out_size, void* d_ws, size_t ws_size,
                              hipStream_t stream)
{
    const float* x    = (const float*)d_in[0];
    const float* x_gt = (const float*)d_in[1];
    const float* Wc   = (const float*)d_in[2];
    const float* bc   = (const float*)d_in[3];
    const float* W1   = (const float*)d_in[4];
    const float* b1   = (const float*)d_in[5];
    const float* W2   = (const float*)d_in[6];
    const float* b2   = (const float*)d_in[7];
    const float* Wrc  = (const float*)d_in[8];
    const float* brc  = (const float*)d_in[9];
    float* out = (float*)d_out;

    const size_t lab_bytes = (size_t)HWP * sizeof(int);
    const size_t xT_bytes  = (size_t)HWP * 128 * sizeof(float);
    int use_xT = (ws_size >= lab_bytes + xT_bytes) ? 1 : 0;

    int*   labels = (int*)d_ws;
    float* xT     = (float*)((char*)d_ws + lab_bytes);

    hipLaunchKernelGGL(k1_classify, dim3(HH, 10), dim3(256), 0, stream,
                       x, x_gt, Wc, bc, out + 2 * (size_t)HWP, labels, xT, use_xT);
    hipLaunchKernelGGL(k2_experts, dim3(CC, HH), dim3(256), 0, stream,
                       x, xT, use_xT, labels,
                       W1, b1, W2, b2, Wrc, brc, out);
}

// Round 2
// 447.057 us; speedup vs baseline: 2.6040x; 2.6040x over previous
//
#include <hip/hip_runtime.h>
#include <hip/hip_bf16.h>

#define HH 448
#define WW 608
#define CC 128
#define HWP (HH*WW)

typedef __attribute__((ext_vector_type(8))) short bf16x8;
typedef __attribute__((ext_vector_type(4))) float f32x4;

__device__ __forceinline__ ushort f2b(float f) {
    __hip_bfloat16 b = __float2bfloat16(f);
    return *reinterpret_cast<ushort*>(&b);
}
__device__ __forceinline__ float b2f(ushort u) {
    union { unsigned v; float f; } x; x.v = ((unsigned)u) << 16; return x.f;
}

// Wcs swizzle: [m][k], k<128. group = (k>>3) ^ (m&15) -> frag reads 2-way (free)
__device__ __forceinline__ int swzA(int m, int k) {
    return m * 128 + ((((k >> 3) ^ (m & 15)) & 15) << 3) + (k & 7);
}
// Xs swizzle: [n][k], k<64. group = (k>>3) ^ (n&7) ^ ((n>>3)&7)
__device__ __forceinline__ int swzB(int n, int k) {
    return n * 64 + ((((k >> 3) ^ (n & 7) ^ ((n >> 3) & 7)) & 7) << 3) + (k & 7);
}

// ---------------- Kernel 1: MFMA classifier + in-register softmax/loss ----------------
// grid (5, 448), block 512 (8 waves). Block = (w-tile of 128, row h).
__global__ __launch_bounds__(512, 4) void k1_mfma(
    const float* __restrict__ x, const float* __restrict__ x_gt,
    const float* __restrict__ Wc, const float* __restrict__ bc,
    float* __restrict__ loss_out, int* __restrict__ labels,
    ushort* __restrict__ xT, int use_xT)
{
    __shared__ ushort Wcs[128 * 128];   // 32 KB, A matrix (classes x K)
    __shared__ ushort Xs[128 * 64];     // 16 KB, B matrix (pixels x K-half)
    __shared__ float bcs[128];

    const int h  = blockIdx.y;
    const int w0 = blockIdx.x * 128;
    const int t  = threadIdx.x;
    const int wv = t >> 6, l = t & 63;
    const int q  = l >> 4, lm = l & 15;
    const int nvalid = (WW - w0 < 128) ? (WW - w0) : 128;

    // stage Wc[h] (fp32 -> bf16, swizzled): 4096 float4s / 512 threads
    const float* Wch = Wc + (size_t)h * (CC * 128);
    #pragma unroll
    for (int it = 0; it < 8; ++it) {
        int f4 = t + (it << 9);
        float4 v = reinterpret_cast<const float4*>(Wch)[f4];
        int e = f4 << 2; int m = e >> 7, kk = e & 127;
        ushort4 u = make_ushort4(f2b(v.x), f2b(v.y), f2b(v.z), f2b(v.w));
        *reinterpret_cast<ushort4*>(&Wcs[swzA(m, kk)]) = u;
    }
    if (t < 128) bcs[t] = bc[h * CC + t];

    f32x4 acc[8];
    #pragma unroll
    for (int mt = 0; mt < 8; ++mt) acc[mt] = (f32x4){0.f, 0.f, 0.f, 0.f};

    for (int kh = 0; kh < 2; ++kh) {
        if (kh) __syncthreads();   // protect Xs from previous readers
        // stage x rows [kh*64, kh*64+64), cols [w0, w0+128) -> bf16 swizzled
        #pragma unroll
        for (int it = 0; it < 2; ++it) {
            int p = t + (it << 9);            // 0..1023
            int i2 = p >> 5;                  // 0..31 (pairs of rows)
            int w = (p & 31) << 2;            // 0..124
            float4 v0, v1;
            if (w0 + w < WW) {
                const float* xb = x + ((size_t)(kh * 64 + i2 * 2)) * HWP + (size_t)h * WW + w0 + w;
                v0 = *reinterpret_cast<const float4*>(xb);
                v1 = *reinterpret_cast<const float4*>(xb + HWP);
            } else { v0 = make_float4(0, 0, 0, 0); v1 = v0; }
            int il = i2 << 1;
            *reinterpret_cast<ushort2*>(&Xs[swzB(w + 0, il)]) = make_ushort2(f2b(v0.x), f2b(v1.x));
            *reinterpret_cast<ushort2*>(&Xs[swzB(w + 1, il)]) = make_ushort2(f2b(v0.y), f2b(v1.y));
            *reinterpret_cast<ushort2*>(&Xs[swzB(w + 2, il)]) = make_ushort2(f2b(v0.z), f2b(v1.z));
            *reinterpret_cast<ushort2*>(&Xs[swzB(w + 3, il)]) = make_ushort2(f2b(v0.w), f2b(v1.w));
        }
        __syncthreads();

        // MFMA: wave wv owns cols [wv*16, wv*16+16), all 128 classes
        #pragma unroll
        for (int kk = 0; kk < 2; ++kk) {
            const int kb = (kk << 5) + (q << 3);        // local k base
            const int kg = (kh << 6) + kb;              // global k base
            bf16x8 bfrag = *reinterpret_cast<const bf16x8*>(&Xs[swzB((wv << 4) + lm, kb)]);
            #pragma unroll
            for (int mt = 0; mt < 8; ++mt) {
                bf16x8 afrag = *reinterpret_cast<const bf16x8*>(&Wcs[swzA((mt << 4) + lm, kg)]);
                acc[mt] = __builtin_amdgcn_mfma_f32_16x16x32_bf16(afrag, bfrag, acc[mt], 0, 0, 0);
            }
        }

        // write xT (bf16) for this K-half
        if (use_xT) {
            #pragma unroll
            for (int it = 0; it < 2; ++it) {
                int g = t + (it << 9);     // 0..1023
                int n = g >> 3, i8 = g & 7;
                if (n < nvalid) {
                    bf16x8 v = *reinterpret_cast<const bf16x8*>(&Xs[swzB(n, i8 << 3)]);
                    *reinterpret_cast<bf16x8*>(xT + ((size_t)(h * WW + w0 + n)) * 128 + (kh << 6) + (i8 << 3)) = v;
                }
            }
        }
    }

    // ---- bias + lrelu + softmax + loss, all in registers ----
    // lane holds col cn = wv*16+lm; rows mt*16 + q*4 + r; 4 lanes (q) share a col
    const int cn = (wv << 4) + lm;
    const int w  = w0 + cn;
    float mx = -1e30f;
    #pragma unroll
    for (int mt = 0; mt < 8; ++mt)
        #pragma unroll
        for (int r = 0; r < 4; ++r) {
            float z = acc[mt][r] + bcs[(mt << 4) + (q << 2) + r];
            z = z > 0.f ? z : 0.01f * z;
            acc[mt][r] = z;
            mx = fmaxf(mx, z);
        }
    mx = fmaxf(mx, __shfl_xor(mx, 16));
    mx = fmaxf(mx, __shfl_xor(mx, 32));
    float s1 = 0.f;
    #pragma unroll
    for (int mt = 0; mt < 8; ++mt)
        #pragma unroll
        for (int r = 0; r < 4; ++r) {
            float ev = __expf(acc[mt][r] - mx);
            acc[mt][r] = ev;
            s1 += ev;
        }
    s1 += __shfl_xor(s1, 16);
    s1 += __shfl_xor(s1, 32);
    const float inv = 1.f / s1;
    float s2 = 0.f;
    #pragma unroll
    for (int mt = 0; mt < 8; ++mt)
        #pragma unroll
        for (int r = 0; r < 4; ++r) s2 += __expf(acc[mt][r] * inv);
    s2 += __shfl_xor(s2, 16);
    s2 += __shfl_xor(s2, 32);

    int lab = 0;
    if (w < WW) {
        float g = x_gt[(size_t)h * WW + w];
        lab = (int)(g * 128.f);
        lab = lab < 0 ? 0 : (lab > 127 ? 127 : lab);
    }
    float pl = 0.f;
    #pragma unroll
    for (int mt = 0; mt < 8; ++mt)
        #pragma unroll
        for (int r = 0; r < 4; ++r)
            if (((mt << 4) + (q << 2) + r) == lab) pl = acc[mt][r] * inv;
    pl += __shfl_xor(pl, 16);
    pl += __shfl_xor(pl, 32);

    if (q == 0 && w < WW) {
        loss_out[(size_t)h * WW + w] = __logf(s2) - pl;
        labels[h * WW + w] = lab;
    }
}

// ---------------- Kernel 2: per-(class, h) expert MLP ----------------
// grid (128, 448), block 256. Thread (j = t>>3, og = t&7): pixel j, 4 outputs.
__global__ __launch_bounds__(256, 8) void k2_experts(
    const float* __restrict__ x, const ushort* __restrict__ xT, int use_xT,
    const int* __restrict__ labels,
    const float* __restrict__ W1, const float* __restrict__ b1,
    const float* __restrict__ W2, const float* __restrict__ b2,
    const float* __restrict__ Wrc, const float* __restrict__ brc,
    float* __restrict__ out)
{
    const int c = blockIdx.x, h = blockIdx.y;
    __shared__ ushort wlist[WW];
    __shared__ int cnt;
    __shared__ ushort W1s[128 * 32];   // bf16 [i][o], 8 KB
    __shared__ float  W2s[32 * 32];    // fp32 [i][o], 4 KB
    __shared__ float  Wrcs[64];
    __shared__ float  b1s[32], b2s[32], brcs[2];
    __shared__ float  xsh[8][128];
    __shared__ float  hs[8][33];
    __shared__ float  h2s[8][33];

    const int t = threadIdx.x;
    const int ln = t & 63;
    if (t == 0) cnt = 0;
    __syncthreads();

    // ballot-based compaction of matching pixels (order irrelevant)
    const int* lrow = labels + h * WW;
    #pragma unroll
    for (int pass = 0; pass < 3; ++pass) {
        int w = pass * 256 + t;
        bool m = (w < WW) && (lrow[w] == c);
        unsigned long long mask = __ballot(m);
        int base = 0;
        if (ln == 0 && mask) base = atomicAdd(&cnt, __popcll(mask));
        base = __shfl(base, 0);
        if (m) wlist[base + __popcll(mask & ((1ull << ln) - 1))] = (ushort)w;
    }
    __syncthreads();
    const int k = cnt;
    if (k == 0) return;

    // stage expert weights (vectorized; W1 as bf16)
    const size_t e = (size_t)h * CC + c;
    {
        const float4* W1p = reinterpret_cast<const float4*>(W1 + e * 4096);
        #pragma unroll
        for (int it = 0; it < 4; ++it) {
            float4 v = W1p[t + (it << 8)];
            *reinterpret_cast<ushort4*>(&W1s[(t + (it << 8)) << 2]) =
                make_ushort4(f2b(v.x), f2b(v.y), f2b(v.z), f2b(v.w));
        }
        reinterpret_cast<float4*>(W2s)[t & 255] = reinterpret_cast<const float4*>(W2 + e * 1024)[t & 255];
        if (t < 16)                 reinterpret_cast<float4*>(Wrcs)[t]    = reinterpret_cast<const float4*>(Wrc + e * 64)[t];
        else if (t >= 32 && t < 40) reinterpret_cast<float4*>(b1s)[t-32]  = reinterpret_cast<const float4*>(b1 + e * 32)[t-32];
        else if (t >= 64 && t < 72) reinterpret_cast<float4*>(b2s)[t-64]  = reinterpret_cast<const float4*>(b2 + e * 32)[t-64];
        else if (t >= 96 && t < 98) brcs[t-96] = brc[e * 2 + (t - 96)];
    }
    __syncthreads();

    const int j = t >> 3, og = t & 7;
    for (int base0 = 0; base0 < k; base0 += 8) {
        const int nb = (k - base0 < 8) ? (k - base0) : 8;
        for (int e2 = t; e2 < (nb << 6); e2 += 256) {
            int jj = e2 >> 6, i2 = e2 & 63;
            int w = wlist[base0 + jj];
            if (use_xT) {
                ushort2 u = reinterpret_cast<const ushort2*>(xT + ((size_t)(h * WW + w)) * 128)[i2];
                xsh[jj][i2 * 2]     = b2f(u.x);
                xsh[jj][i2 * 2 + 1] = b2f(u.y);
            } else {
                size_t bx = (size_t)(i2 * 2) * HWP + (size_t)h * WW + w;
                xsh[jj][i2 * 2]     = x[bx];
                xsh[jj][i2 * 2 + 1] = x[bx + HWP];
            }
        }
        __syncthreads();

        if (j < nb) {   // layer 1: 128 -> 32 (4 outputs per thread)
            float4 a = reinterpret_cast<const float4*>(b1s)[og];
            #pragma unroll 16
            for (int i = 0; i < 128; ++i) {
                float xv = xsh[j][i];
                ushort4 w4 = *reinterpret_cast<const ushort4*>(&W1s[(i << 5) + (og << 2)]);
                a.x = fmaf(xv, b2f(w4.x), a.x);
                a.y = fmaf(xv, b2f(w4.y), a.y);
                a.z = fmaf(xv, b2f(w4.z), a.z);
                a.w = fmaf(xv, b2f(w4.w), a.w);
            }
            hs[j][(og << 2) + 0] = a.x > 0.f ? a.x : 0.01f * a.x;
            hs[j][(og << 2) + 1] = a.y > 0.f ? a.y : 0.01f * a.y;
            hs[j][(og << 2) + 2] = a.z > 0.f ? a.z : 0.01f * a.z;
            hs[j][(og << 2) + 3] = a.w > 0.f ? a.w : 0.01f * a.w;
        }
        __syncthreads();
        if (j < nb) {   // layer 2: 32 -> 32
            float4 a = reinterpret_cast<const float4*>(b2s)[og];
            #pragma unroll
            for (int i = 0; i < 32; ++i) {
                float xv = hs[j][i];
                float4 w4 = *reinterpret_cast<const float4*>(&W2s[(i << 5) + (og << 2)]);
                a.x = fmaf(xv, w4.x, a.x);
                a.y = fmaf(xv, w4.y, a.y);
                a.z = fmaf(xv, w4.z, a.z);
                a.w = fmaf(xv, w4.w, a.w);
            }
            h2s[j][(og << 2) + 0] = a.x > 0.f ? a.x : 0.01f * a.x;
            h2s[j][(og << 2) + 1] = a.y > 0.f ? a.y : 0.01f * a.y;
            h2s[j][(og << 2) + 2] = a.z > 0.f ? a.z : 0.01f * a.z;
            h2s[j][(og << 2) + 3] = a.w > 0.f ? a.w : 0.01f * a.w;
        }
        __syncthreads();
        if (j < nb && og < 2) {   // layer 3: 32 -> 2
            float a = brcs[og];
            #pragma unroll
            for (int i = 0; i < 32; ++i) a = fmaf(h2s[j][i], Wrcs[(i << 1) + og], a);
            a = a > 0.f ? a : 0.01f * a;
            int pix = h * WW + wlist[base0 + j];
            if (og == 1) out[HWP + pix] = a;
            else         out[pix] = ((float)c + a) * (1.0f / 128.0f);
        }
        __syncthreads();
    }
}

extern "C" void kernel_launch(void* const* d_in, const int* in_sizes, int n_in,
                              void* d_out, int out_size, void* d_ws, size_t ws_size,
                              hipStream_t stream)
{
    const float* x    = (const float*)d_in[0];
    const float* x_gt = (const float*)d_in[1];
    const float* Wc   = (const float*)d_in[2];
    const float* bc   = (const float*)d_in[3];
    const float* W1   = (const float*)d_in[4];
    const float* b1   = (const float*)d_in[5];
    const float* W2   = (const float*)d_in[6];
    const float* b2   = (const float*)d_in[7];
    const float* Wrc  = (const float*)d_in[8];
    const float* brc  = (const float*)d_in[9];
    float* out = (float*)d_out;

    const size_t lab_bytes = (size_t)HWP * sizeof(int);
    const size_t xT_bytes  = (size_t)HWP * 128 * sizeof(ushort);
    int use_xT = (ws_size >= lab_bytes + xT_bytes) ? 1 : 0;

    int*    labels = (int*)d_ws;
    ushort* xT     = (ushort*)((char*)d_ws + lab_bytes);

    hipLaunchKernelGGL(k1_mfma, dim3(5, HH), dim3(512), 0, stream,
                       x, x_gt, Wc, bc, out + 2 * (size_t)HWP, labels, xT, use_xT);
    hipLaunchKernelGGL(k2_experts, dim3(CC, HH), dim3(256), 0, stream,
                       x, xT, use_xT, labels,
                       W1, b1, W2, b2, Wrc, brc, out);
}